// Round 1
// baseline (1005.950 us; speedup 1.0000x reference)
//
#include <hip/hip_runtime.h>
#include <hip/hip_bf16.h>

typedef unsigned short u16;
typedef __attribute__((ext_vector_type(8))) short bf16x8;
typedef __attribute__((ext_vector_type(4))) float f32x4;

__device__ __forceinline__ u16 f2bf(float f) {
  union { float f; unsigned u; } v; v.f = f;
  unsigned r = v.u + 0x7fffu + ((v.u >> 16) & 1u);
  return (u16)(r >> 16);
}

__device__ __forceinline__ void gload_lds16(const void* g, void* l) {
  __builtin_amdgcn_global_load_lds(
      (const __attribute__((address_space(1))) unsigned int*)g,
      (__attribute__((address_space(3))) unsigned int*)l, 16, 0, 0);
}

// ---------------- convert f32 -> bf16, vectorized ----------------
__global__ __launch_bounds__(256) void cvt_f32_bf16(const float* __restrict__ in,
                                                    u16* __restrict__ out, int n4) {
  int i = blockIdx.x * 256 + threadIdx.x;
  if (i < n4) {
    float4 v = ((const float4*)in)[i];
    ushort4 o;
    o.x = f2bf(v.x); o.y = f2bf(v.y); o.z = f2bf(v.z); o.w = f2bf(v.w);
    ((ushort4*)out)[i] = o;
  }
}

// -------- transpose [K][N] f32 -> [Npad][K] bf16 (pad rows = 0) --------
// grid: (Npad/32, K/32), block 256
__global__ __launch_bounds__(256) void transpose_w(const float* __restrict__ W,
                                                   u16* __restrict__ Wt,
                                                   int K, int N) {
  __shared__ float tile[32][33];
  const int tx = threadIdx.x & 31, ty = threadIdx.x >> 5;  // 32 x 8
  const int n0 = blockIdx.x * 32, k0 = blockIdx.y * 32;
#pragma unroll
  for (int i = 0; i < 32; i += 8) {
    int k = k0 + ty + i, n = n0 + tx;
    tile[ty + i][tx] = (n < N) ? W[(size_t)k * N + n] : 0.0f;
  }
  __syncthreads();
#pragma unroll
  for (int i = 0; i < 32; i += 8) {
    int n = n0 + ty + i, k = k0 + tx;
    Wt[(size_t)n * K + k] = f2bf(tile[tx][ty + i]);
  }
}

// ---------------- GEMM: C[M][ldc] = act(A[M][K] @ Bt[N][K]^T + bias) ----------
// 128x128 tile, BK=32, 4 waves (2x2), each wave 64x64 via 4x4 of 16x16x32 MFMA.
template <int RELU, int F32OUT, int NCHECK>
__global__ __launch_bounds__(256, 2)
void gemm_bt(const u16* __restrict__ A, const u16* __restrict__ Bt,
             const float* __restrict__ bias, void* __restrict__ C,
             int K, int N, int ldc) {
  __shared__ u16 As[128 * 32];
  __shared__ u16 Bs[128 * 32];
  const int t = threadIdx.x;
  const int w = t >> 6, lane = t & 63;
  const int bm = blockIdx.x, bn = blockIdx.y;
  const int wr = (w >> 1) * 64, wc = (w & 1) * 64;

  f32x4 acc[4][4];
#pragma unroll
  for (int m = 0; m < 4; m++)
#pragma unroll
    for (int n = 0; n < 4; n++) acc[m][n] = f32x4{0.f, 0.f, 0.f, 0.f};

  const u16* gA = A + (size_t)(bm * 128 + (t >> 2)) * K + (t & 3) * 8;
  const u16* gB = Bt + (size_t)(bn * 128 + (t >> 2)) * K + (t & 3) * 8;
  u16* lA = As + w * 512;   // wave-uniform LDS dest (lane*16B added by HW)
  u16* lB = Bs + w * 512;
  const size_t row64 = (size_t)64 * K;

  for (int k0 = 0; k0 < K; k0 += 32) {
    gload_lds16(gA + k0, lA);
    gload_lds16(gA + row64 + k0, lA + 2048);
    gload_lds16(gB + k0, lB);
    gload_lds16(gB + row64 + k0, lB + 2048);
    asm volatile("s_waitcnt vmcnt(0)" ::: "memory");
    __syncthreads();

    const u16* pa = As + (wr + (lane & 15)) * 32 + (lane >> 4) * 8;
    const u16* pb = Bs + (wc + (lane & 15)) * 32 + (lane >> 4) * 8;
    bf16x8 af[4], bfr[4];
#pragma unroll
    for (int m = 0; m < 4; m++) af[m] = *(const bf16x8*)(pa + m * 512);
#pragma unroll
    for (int n = 0; n < 4; n++) bfr[n] = *(const bf16x8*)(pb + n * 512);
#pragma unroll
    for (int m = 0; m < 4; m++)
#pragma unroll
      for (int n = 0; n < 4; n++)
        acc[m][n] = __builtin_amdgcn_mfma_f32_16x16x32_bf16(af[m], bfr[n], acc[m][n], 0, 0, 0);
    __syncthreads();
  }

  const int crow = bm * 128 + wr + (lane >> 4) * 4;
  const int ccol = bn * 128 + wc + (lane & 15);
#pragma unroll
  for (int n = 0; n < 4; n++) {
    const int col = ccol + n * 16;
    if (NCHECK && col >= N) continue;
    const float bv = bias[col];
#pragma unroll
    for (int m = 0; m < 4; m++) {
#pragma unroll
      for (int r = 0; r < 4; r++) {
        const int row = crow + m * 16 + r;
        float v = acc[m][n][r] + bv;
        if (RELU) v = fmaxf(v, 0.0f);
        if (F32OUT)
          ((float*)C)[(size_t)row * ldc + col] = v;
        else
          ((u16*)C)[(size_t)row * ldc + col] = f2bf(v);
      }
    }
  }
}

// ---------------- row softmax: one wave per row ----------------
__global__ __launch_bounds__(256) void softmax_rows(const float* __restrict__ logits,
                                                    float* __restrict__ out,
                                                    int rows, int cols) {
  const int wid = (blockIdx.x * 256 + threadIdx.x) >> 6;
  const int lane = threadIdx.x & 63;
  if (wid >= rows) return;
  const float* rp = logits + (size_t)wid * cols;
  float v[16];
  float mx = -1e30f;
#pragma unroll
  for (int j = 0; j < 16; j++) {
    int c = lane + j * 64;
    v[j] = (c < cols) ? rp[c] : -1e30f;
    mx = fmaxf(mx, v[j]);
  }
#pragma unroll
  for (int s = 32; s; s >>= 1) mx = fmaxf(mx, __shfl_xor(mx, s));
  float sum = 0.f;
#pragma unroll
  for (int j = 0; j < 16; j++) {
    v[j] = __expf(v[j] - mx);
    sum += v[j];
  }
#pragma unroll
  for (int s = 32; s; s >>= 1) sum += __shfl_xor(sum, s);
  const float inv = 1.0f / sum;
  float* op = out + (size_t)wid * cols;
#pragma unroll
  for (int j = 0; j < 16; j++) {
    int c = lane + j * 64;
    if (c < cols) op[c] = v[j] * inv;
  }
}

extern "C" void kernel_launch(void* const* d_in, const int* in_sizes, int n_in,
                              void* d_out, int out_size, void* d_ws, size_t ws_size,
                              hipStream_t stream) {
  const float* x  = (const float*)d_in[0];
  const float* W1 = (const float*)d_in[1];
  const float* b1 = (const float*)d_in[2];
  const float* W2 = (const float*)d_in[3];
  const float* b2 = (const float*)d_in[4];
  const float* Wc = (const float*)d_in[5];
  const float* bc = (const float*)d_in[6];
  float* out = (float*)d_out;

  const int B = 8192, D = 4096, DOUT = 1000, DOUTP = 1024;

  char* ws = (char*)d_ws;
  u16* xb     = (u16*)(ws + 0);                       // 8192x4096 bf16 (67.1MB)
  u16* h      = (u16*)(ws + 67108864);                // 8192x4096 bf16
  u16* feats  = xb;                                   // alias: x dead after GEMM1
  u16* W1t    = (u16*)(ws + 134217728);               // 4096x4096 bf16 [N][K]
  u16* W2t    = (u16*)(ws + 167772160);               // 4096x4096 bf16 [N][K]
  u16* Wct    = (u16*)(ws + 201326592);               // 1024x4096 bf16 [Npad][K]
  float* logits = (float*)(ws + 209715200);           // 8192x1000 f32

  // stage 0: dtype conversions / transposes
  cvt_f32_bf16<<<(B * D / 4 + 255) / 256, 256, 0, stream>>>(x, xb, B * D / 4);
  transpose_w<<<dim3(D / 32, D / 32), 256, 0, stream>>>(W1, W1t, D, D);
  transpose_w<<<dim3(D / 32, D / 32), 256, 0, stream>>>(W2, W2t, D, D);
  transpose_w<<<dim3(DOUTP / 32, D / 32), 256, 0, stream>>>(Wc, Wct, D, DOUT);

  // stage 1: h = relu(x@W1+b1)
  gemm_bt<1, 0, 0><<<dim3(B / 128, D / 128), 256, 0, stream>>>(xb, W1t, b1, h, D, D, D);
  // stage 2: feats = relu(h@W2+b2)
  gemm_bt<1, 0, 0><<<dim3(B / 128, D / 128), 256, 0, stream>>>(h, W2t, b2, feats, D, D, D);
  // stage 3: logits = feats@Wc+bc  (f32, N bounds-checked)
  gemm_bt<0, 1, 1><<<dim3(B / 128, DOUTP / 128), 256, 0, stream>>>(feats, Wct, bc, logits, D, DOUT, DOUT);
  // stage 4: softmax rows
  softmax_rows<<<(B * 64 + 255) / 256, 256, 0, stream>>>(logits, out, B, DOUT);
}

// Round 2
// 896.077 us; speedup vs baseline: 1.1226x; 1.1226x over previous
//
#include <hip/hip_runtime.h>
#include <hip/hip_bf16.h>

typedef unsigned short u16;
typedef __attribute__((ext_vector_type(8))) short bf16x8;
typedef __attribute__((ext_vector_type(4))) float f32x4;

#define MFMA __builtin_amdgcn_mfma_f32_16x16x32_bf16

__device__ __forceinline__ u16 f2bf(float f) {
  union { float f; unsigned u; } v; v.f = f;
  unsigned r = v.u + 0x7fffu + ((v.u >> 16) & 1u);
  return (u16)(r >> 16);
}

__device__ __forceinline__ void gload_lds16(const void* g, void* l) {
  __builtin_amdgcn_global_load_lds(
      (const __attribute__((address_space(1))) unsigned int*)g,
      (__attribute__((address_space(3))) unsigned int*)l, 16, 0, 0);
}

// ---------------- convert f32 -> bf16, vectorized ----------------
__global__ __launch_bounds__(256) void cvt_f32_bf16(const float* __restrict__ in,
                                                    u16* __restrict__ out, int n4) {
  int i = blockIdx.x * 256 + threadIdx.x;
  if (i < n4) {
    float4 v = ((const float4*)in)[i];
    ushort4 o;
    o.x = f2bf(v.x); o.y = f2bf(v.y); o.z = f2bf(v.z); o.w = f2bf(v.w);
    ((ushort4*)out)[i] = o;
  }
}

// -------- transpose [K][N] f32 -> [Npad][K] bf16 (pad rows = 0) --------
__global__ __launch_bounds__(256) void transpose_w(const float* __restrict__ W,
                                                   u16* __restrict__ Wt,
                                                   int K, int N) {
  __shared__ float tile[32][33];
  const int tx = threadIdx.x & 31, ty = threadIdx.x >> 5;  // 32 x 8
  const int n0 = blockIdx.x * 32, k0 = blockIdx.y * 32;
#pragma unroll
  for (int i = 0; i < 32; i += 8) {
    int k = k0 + ty + i, n = n0 + tx;
    tile[ty + i][tx] = (n < N) ? W[(size_t)k * N + n] : 0.0f;
  }
  __syncthreads();
#pragma unroll
  for (int i = 0; i < 32; i += 8) {
    int n = n0 + ty + i, k = k0 + tx;
    Wt[(size_t)n * K + k] = f2bf(tile[tx][ty + i]);
  }
}

// =====================================================================
// 256x256 8-phase GEMM (BK=64, 8 waves 2Mx4N, per-wave 128x64 output).
// C[M][N] = act(A[M][K] @ Bt[N][K]^T + bias), bf16 in/out, f32 acc.
// LDS 128KB: [buf][A u0|A u1|B u0|B u1], 16KB units, st-swizzled.
// Schedule per K-tile t (4 phases): reads {A_u0+B_u0, B_u1, A_u1, -};
// stages {A_u1(t+1), A_u0(t+2), B_u0(t+2), B_u1(t+2)}; vmcnt(6) @ ph4.
// =====================================================================
#define STAGE_A(U, TK) do { int _tk=(TK); \
    char* _l = lds + ((_tk & 1) << 16) + ((U) << 14) + (w << 10); \
    const u16* _g = Ag + _tk * 64; \
    gload_lds16(_g + aoff[U][0], _l); \
    gload_lds16(_g + aoff[U][1], _l + 8192); } while (0)
#define STAGE_B(U, TK) do { int _tk=(TK); \
    char* _l = lds + ((_tk & 1) << 16) + 32768 + ((U) << 14) + (w << 10); \
    const u16* _g = Bg + _tk * 64; \
    gload_lds16(_g + boff[U][0], _l); \
    gload_lds16(_g + boff[U][1], _l + 8192); } while (0)

template <int RELU>
__global__ __launch_bounds__(512, 2)
void gemm256(const u16* __restrict__ A, const u16* __restrict__ Bt,
             const float* __restrict__ bias, u16* __restrict__ C,
             int K, int N, int nbn) {
  __shared__ char lds[131072];
  const int tid = threadIdx.x;
  const int w = tid >> 6, lane = tid & 63;
  const int wm = w >> 2, wn = w & 3;
  const int l15 = lane & 15, l4 = lane >> 4;

  // XCD-aware swizzle (nwg % 8 == 0)
  const int nwg = (int)gridDim.x;
  const int q = nwg >> 3;
  const int wgid = ((int)blockIdx.x & 7) * q + ((int)blockIdx.x >> 3);
  const int bm = wgid / nbn, bn = wgid % nbn;

  // staging constants: chunk c = tid; 64-row x 64-col block per 8KB
  const int rb = tid >> 3;                  // row in block
  const int gslot = (tid & 7) ^ (rb & 7);   // inverse-swizzled k-slot
  unsigned aoff[2][2], boff[2][2];
#pragma unroll
  for (int u = 0; u < 2; u++)
#pragma unroll
    for (int b = 0; b < 2; b++) {
      aoff[u][b] = (unsigned)(b * 128 + u * 64 + rb) * (unsigned)K + gslot * 8;
      int brow = (2 * b + (rb >> 5)) * 64 + u * 32 + (rb & 31);
      boff[u][b] = (unsigned)brow * (unsigned)K + gslot * 8;
    }
  const u16* Ag = A + (size_t)bm * 256 * K;
  const u16* Bg = Bt + (size_t)bn * 256 * K;

  // ds_read constants (swizzled): slot(ks) = (ks*4 + l4) ^ (l15 & 7)
  const int s0 = ((l4) ^ (l15 & 7)) << 4;
  const int s1 = ((4 + l4) ^ (l15 & 7)) << 4;
  const int pA0 = (wm << 13) + (l15 << 7);
  const int pB0 = 32768 + ((wn >> 1) << 13) + ((((wn & 1) << 5) + l15) << 7);

  bf16x8 a[4][2], b[4][2];
  f32x4 acc[8][4];
#pragma unroll
  for (int m = 0; m < 8; m++)
#pragma unroll
    for (int n = 0; n < 4; n++) acc[m][n] = f32x4{0.f, 0.f, 0.f, 0.f};

  // ---- prologue: tile0 full + tile1 {A_u0,B_u0,B_u1}; keep 3 units in flight
  STAGE_A(0, 0); STAGE_A(1, 0); STAGE_B(0, 0); STAGE_B(1, 0);
  STAGE_A(0, 1); STAGE_B(0, 1); STAGE_B(1, 1);
  asm volatile("s_waitcnt vmcnt(6)" ::: "memory");
  __builtin_amdgcn_s_barrier();

  const int nt = K >> 6;
  for (int t = 0; t < nt; t++) {
    const char* bp = lds + ((t & 1) << 16);
    // ---------- phase 1: (M0, N0-1); stage A_u1(t+1) ----------
#pragma unroll
    for (int mi = 0; mi < 4; mi++) {
      a[mi][0] = *(const bf16x8*)(bp + pA0 + mi * 2048 + s0);
      a[mi][1] = *(const bf16x8*)(bp + pA0 + mi * 2048 + s1);
    }
#pragma unroll
    for (int n = 0; n < 2; n++) {
      b[n][0] = *(const bf16x8*)(bp + pB0 + n * 2048 + s0);
      b[n][1] = *(const bf16x8*)(bp + pB0 + n * 2048 + s1);
    }
    if (t + 1 < nt) STAGE_A(1, t + 1);
    __builtin_amdgcn_s_barrier();
    asm volatile("s_waitcnt lgkmcnt(0)" ::: "memory");
    __builtin_amdgcn_sched_barrier(0);
    __builtin_amdgcn_s_setprio(1);
#pragma unroll
    for (int mi = 0; mi < 4; mi++) {
      acc[mi][0] = MFMA(a[mi][0], b[0][0], acc[mi][0], 0, 0, 0);
      acc[mi][0] = MFMA(a[mi][1], b[0][1], acc[mi][0], 0, 0, 0);
      acc[mi][1] = MFMA(a[mi][0], b[1][0], acc[mi][1], 0, 0, 0);
      acc[mi][1] = MFMA(a[mi][1], b[1][1], acc[mi][1], 0, 0, 0);
    }
    __builtin_amdgcn_s_setprio(0);
    __builtin_amdgcn_s_barrier();
    // ---------- phase 2: (M0, N2-3); stage A_u0(t+2) ----------
#pragma unroll
    for (int n = 0; n < 2; n++) {
      b[2 + n][0] = *(const bf16x8*)(bp + pB0 + 16384 + n * 2048 + s0);
      b[2 + n][1] = *(const bf16x8*)(bp + pB0 + 16384 + n * 2048 + s1);
    }
    if (t + 2 < nt) STAGE_A(0, t + 2);
    __builtin_amdgcn_s_barrier();
    asm volatile("s_waitcnt lgkmcnt(0)" ::: "memory");
    __builtin_amdgcn_sched_barrier(0);
    __builtin_amdgcn_s_setprio(1);
#pragma unroll
    for (int mi = 0; mi < 4; mi++) {
      acc[mi][2] = MFMA(a[mi][0], b[2][0], acc[mi][2], 0, 0, 0);
      acc[mi][2] = MFMA(a[mi][1], b[2][1], acc[mi][2], 0, 0, 0);
      acc[mi][3] = MFMA(a[mi][0], b[3][0], acc[mi][3], 0, 0, 0);
      acc[mi][3] = MFMA(a[mi][1], b[3][1], acc[mi][3], 0, 0, 0);
    }
    __builtin_amdgcn_s_setprio(0);
    __builtin_amdgcn_s_barrier();
    // ---------- phase 3: (M1, N2-3); stage B_u0(t+2) ----------
#pragma unroll
    for (int mi = 0; mi < 4; mi++) {
      a[mi][0] = *(const bf16x8*)(bp + 16384 + pA0 + mi * 2048 + s0);
      a[mi][1] = *(const bf16x8*)(bp + 16384 + pA0 + mi * 2048 + s1);
    }
    if (t + 2 < nt) STAGE_B(0, t + 2);
    __builtin_amdgcn_s_barrier();
    asm volatile("s_waitcnt lgkmcnt(0)" ::: "memory");
    __builtin_amdgcn_sched_barrier(0);
    __builtin_amdgcn_s_setprio(1);
#pragma unroll
    for (int mi = 0; mi < 4; mi++) {
      acc[4 + mi][2] = MFMA(a[mi][0], b[2][0], acc[4 + mi][2], 0, 0, 0);
      acc[4 + mi][2] = MFMA(a[mi][1], b[2][1], acc[4 + mi][2], 0, 0, 0);
      acc[4 + mi][3] = MFMA(a[mi][0], b[3][0], acc[4 + mi][3], 0, 0, 0);
      acc[4 + mi][3] = MFMA(a[mi][1], b[3][1], acc[4 + mi][3], 0, 0, 0);
    }
    __builtin_amdgcn_s_setprio(0);
    __builtin_amdgcn_s_barrier();
    // ---------- phase 4: (M1, N0-1); stage B_u1(t+2); vmcnt(6) ----------
    if (t + 2 < nt) STAGE_B(1, t + 2);
    __builtin_amdgcn_s_setprio(1);
#pragma unroll
    for (int mi = 0; mi < 4; mi++) {
      acc[4 + mi][0] = MFMA(a[mi][0], b[0][0], acc[4 + mi][0], 0, 0, 0);
      acc[4 + mi][0] = MFMA(a[mi][1], b[0][1], acc[4 + mi][0], 0, 0, 0);
      acc[4 + mi][1] = MFMA(a[mi][0], b[1][0], acc[4 + mi][1], 0, 0, 0);
      acc[4 + mi][1] = MFMA(a[mi][1], b[1][1], acc[4 + mi][1], 0, 0, 0);
    }
    __builtin_amdgcn_s_setprio(0);
    if (t + 2 < nt) { asm volatile("s_waitcnt vmcnt(6)" ::: "memory"); }
    else            { asm volatile("s_waitcnt vmcnt(0)" ::: "memory"); }
    __builtin_amdgcn_s_barrier();
  }

  // ---------- epilogue: bias + act + bf16 store ----------
  const int crow0 = bm * 256 + wm * 128 + l4 * 4;
  const int ccol0 = bn * 256 + wn * 64 + l15;
#pragma unroll
  for (int n = 0; n < 4; n++) {
    const int col = ccol0 + n * 16;
    const float bv = bias[col];
#pragma unroll
    for (int m = 0; m < 8; m++) {
#pragma unroll
      for (int r = 0; r < 4; r++) {
        const int row = crow0 + m * 16 + r;
        float v = acc[m][n][r] + bv;
        if (RELU) v = fmaxf(v, 0.0f);
        C[(size_t)row * N + col] = f2bf(v);
      }
    }
  }
}

// ---------------- 128x128 GEMM (validated round-1) for the small head ----
template <int RELU, int F32OUT, int NCHECK>
__global__ __launch_bounds__(256, 2)
void gemm_bt(const u16* __restrict__ A, const u16* __restrict__ Bt,
             const float* __restrict__ bias, void* __restrict__ C,
             int K, int N, int ldc) {
  __shared__ u16 As[128 * 32];
  __shared__ u16 Bs[128 * 32];
  const int t = threadIdx.x;
  const int w = t >> 6, lane = t & 63;
  const int bm = blockIdx.x, bn = blockIdx.y;
  const int wr = (w >> 1) * 64, wc = (w & 1) * 64;

  f32x4 acc[4][4];
#pragma unroll
  for (int m = 0; m < 4; m++)
#pragma unroll
    for (int n = 0; n < 4; n++) acc[m][n] = f32x4{0.f, 0.f, 0.f, 0.f};

  const u16* gA = A + (size_t)(bm * 128 + (t >> 2)) * K + (t & 3) * 8;
  const u16* gB = Bt + (size_t)(bn * 128 + (t >> 2)) * K + (t & 3) * 8;
  u16* lA = As + w * 512;
  u16* lB = Bs + w * 512;
  const size_t row64 = (size_t)64 * K;

  for (int k0 = 0; k0 < K; k0 += 32) {
    gload_lds16(gA + k0, lA);
    gload_lds16(gA + row64 + k0, lA + 2048);
    gload_lds16(gB + k0, lB);
    gload_lds16(gB + row64 + k0, lB + 2048);
    asm volatile("s_waitcnt vmcnt(0)" ::: "memory");
    __syncthreads();

    const u16* pa = As + (wr + (lane & 15)) * 32 + (lane >> 4) * 8;
    const u16* pb = Bs + (wc + (lane & 15)) * 32 + (lane >> 4) * 8;
    bf16x8 af[4], bfr[4];
#pragma unroll
    for (int m = 0; m < 4; m++) af[m] = *(const bf16x8*)(pa + m * 512);
#pragma unroll
    for (int n = 0; n < 4; n++) bfr[n] = *(const bf16x8*)(pb + n * 512);
#pragma unroll
    for (int m = 0; m < 4; m++)
#pragma unroll
      for (int n = 0; n < 4; n++)
        acc[m][n] = MFMA(af[m], bfr[n], acc[m][n], 0, 0, 0);
    __syncthreads();
  }

  const int crow = bm * 128 + wr + (lane >> 4) * 4;
  const int ccol = bn * 128 + wc + (lane & 15);
#pragma unroll
  for (int n = 0; n < 4; n++) {
    const int col = ccol + n * 16;
    if (NCHECK && col >= N) continue;
    const float bv = bias[col];
#pragma unroll
    for (int m = 0; m < 4; m++) {
#pragma unroll
      for (int r = 0; r < 4; r++) {
        const int row = crow + m * 16 + r;
        float v = acc[m][n][r] + bv;
        if (RELU) v = fmaxf(v, 0.0f);
        if (F32OUT)
          ((float*)C)[(size_t)row * ldc + col] = v;
        else
          ((u16*)C)[(size_t)row * ldc + col] = f2bf(v);
      }
    }
  }
}

// ---------------- row softmax: one wave per row ----------------
__global__ __launch_bounds__(256) void softmax_rows(const float* __restrict__ logits,
                                                    float* __restrict__ out,
                                                    int rows, int cols) {
  const int wid = (blockIdx.x * 256 + threadIdx.x) >> 6;
  const int lane = threadIdx.x & 63;
  if (wid >= rows) return;
  const float* rp = logits + (size_t)wid * cols;
  float v[16];
  float mx = -1e30f;
#pragma unroll
  for (int j = 0; j < 16; j++) {
    int c = lane + j * 64;
    v[j] = (c < cols) ? rp[c] : -1e30f;
    mx = fmaxf(mx, v[j]);
  }
#pragma unroll
  for (int s = 32; s; s >>= 1) mx = fmaxf(mx, __shfl_xor(mx, s));
  float sum = 0.f;
#pragma unroll
  for (int j = 0; j < 16; j++) {
    v[j] = __expf(v[j] - mx);
    sum += v[j];
  }
#pragma unroll
  for (int s = 32; s; s >>= 1) sum += __shfl_xor(sum, s);
  const float inv = 1.0f / sum;
  float* op = out + (size_t)wid * cols;
#pragma unroll
  for (int j = 0; j < 16; j++) {
    int c = lane + j * 64;
    if (c < cols) op[c] = v[j] * inv;
  }
}

extern "C" void kernel_launch(void* const* d_in, const int* in_sizes, int n_in,
                              void* d_out, int out_size, void* d_ws, size_t ws_size,
                              hipStream_t stream) {
  const float* x  = (const float*)d_in[0];
  const float* W1 = (const float*)d_in[1];
  const float* b1 = (const float*)d_in[2];
  const float* W2 = (const float*)d_in[3];
  const float* b2 = (const float*)d_in[4];
  const float* Wc = (const float*)d_in[5];
  const float* bc = (const float*)d_in[6];
  float* out = (float*)d_out;

  const int B = 8192, D = 4096, DOUT = 1000, DOUTP = 1024;

  char* ws = (char*)d_ws;
  u16* xb     = (u16*)(ws + 0);                       // 8192x4096 bf16
  u16* h      = (u16*)(ws + 67108864);                // 8192x4096 bf16
  u16* feats  = xb;                                   // alias: x dead after GEMM1
  u16* W1t    = (u16*)(ws + 134217728);               // 4096x4096 bf16 [N][K]
  u16* W2t    = (u16*)(ws + 167772160);               // 4096x4096 bf16 [N][K]
  u16* Wct    = (u16*)(ws + 201326592);               // 1024x4096 bf16 [Npad][K]
  float* logits = (float*)(ws + 209715200);           // 8192x1000 f32

  // stage 0: dtype conversions / transposes
  cvt_f32_bf16<<<(B * D / 4 + 255) / 256, 256, 0, stream>>>(x, xb, B * D / 4);
  transpose_w<<<dim3(D / 32, D / 32), 256, 0, stream>>>(W1, W1t, D, D);
  transpose_w<<<dim3(D / 32, D / 32), 256, 0, stream>>>(W2, W2t, D, D);
  transpose_w<<<dim3(DOUTP / 32, D / 32), 256, 0, stream>>>(Wc, Wct, D, DOUT);

  // stage 1/2: 256^2 8-phase GEMMs (grid 32x16 = 512 blocks)
  gemm256<1><<<dim3(512), 512, 0, stream>>>(xb, W1t, b1, h, D, D, D / 256);
  gemm256<1><<<dim3(512), 512, 0, stream>>>(h, W2t, b2, feats, D, D, D / 256);
  // stage 3: logits = feats@Wc+bc (f32 out, N bounds-checked)
  gemm_bt<0, 1, 1><<<dim3(B / 128, DOUTP / 128), 256, 0, stream>>>(feats, Wct, bc, logits, D, DOUT, DOUT);
  // stage 4: softmax rows
  softmax_rows<<<(B * 64 + 255) / 256, 256, 0, stream>>>(logits, out, B, DOUT);
}

// Round 3
// 873.228 us; speedup vs baseline: 1.1520x; 1.0262x over previous
//
#include <hip/hip_runtime.h>
#include <hip/hip_bf16.h>

typedef unsigned short u16;
typedef __attribute__((ext_vector_type(8))) short bf16x8;
typedef __attribute__((ext_vector_type(4))) float f32x4;

#define MFMA __builtin_amdgcn_mfma_f32_16x16x32_bf16

__device__ __forceinline__ u16 f2bf(float f) {
  union { float f; unsigned u; } v; v.f = f;
  unsigned r = v.u + 0x7fffu + ((v.u >> 16) & 1u);
  return (u16)(r >> 16);
}

__device__ __forceinline__ void gload_lds16(const void* g, void* l) {
  __builtin_amdgcn_global_load_lds(
      (const __attribute__((address_space(1))) unsigned int*)g,
      (__attribute__((address_space(3))) unsigned int*)l, 16, 0, 0);
}

// ---------------- convert f32 -> bf16, vectorized ----------------
__global__ __launch_bounds__(256) void cvt_f32_bf16(const float* __restrict__ in,
                                                    u16* __restrict__ out, int n4) {
  int i = blockIdx.x * 256 + threadIdx.x;
  if (i < n4) {
    float4 v = ((const float4*)in)[i];
    ushort4 o;
    o.x = f2bf(v.x); o.y = f2bf(v.y); o.z = f2bf(v.z); o.w = f2bf(v.w);
    ((ushort4*)out)[i] = o;
  }
}

// -------- transpose [K][N] f32 -> [Npad][K] bf16 (pad rows = 0) --------
__global__ __launch_bounds__(256) void transpose_w(const float* __restrict__ W,
                                                   u16* __restrict__ Wt,
                                                   int K, int N) {
  __shared__ float tile[32][33];
  const int tx = threadIdx.x & 31, ty = threadIdx.x >> 5;  // 32 x 8
  const int n0 = blockIdx.x * 32, k0 = blockIdx.y * 32;
#pragma unroll
  for (int i = 0; i < 32; i += 8) {
    int k = k0 + ty + i, n = n0 + tx;
    tile[ty + i][tx] = (n < N) ? W[(size_t)k * N + n] : 0.0f;
  }
  __syncthreads();
#pragma unroll
  for (int i = 0; i < 32; i += 8) {
    int n = n0 + ty + i, k = k0 + tx;
    Wt[(size_t)n * K + k] = f2bf(tile[tx][ty + i]);
  }
}

// =====================================================================
// 256x256 8-phase GEMM, register-pipelined reads (round-3).
// BK=64, 8 waves 2Mx4N, per-wave 128x64. LDS 128KB dbuf, XOR-swizzled.
// Quadrants: P1=(M0,Blo) P2=(M0,Bhi) P3=(M1,Bhi) P4=(M1,Blo).
// Reads: P1: Blo(t)+Bhi(t); P2: A1(t); P3: A0(t+1); P4: none.
// Stages: P1:A_u1(t+1) P2:A_u0(t+2) P3:B_u0(t+2) P4:B_u1(t+2).
// Waits: vmcnt(6) at end-P2 and end-P4 (derived; certifies A0(t+1) by
// P3(t) read, and all of tile t+1 by P1/P2(t+1) reads).
// =====================================================================
#define STAGE_A(U, TK) do { int _tk=(TK); \
    char* _l = lds + ((_tk & 1) << 16) + ((U) << 14) + (w << 10); \
    const u16* _g = Ag + _tk * 64; \
    gload_lds16(_g + aoff[U][0], _l); \
    gload_lds16(_g + aoff[U][1], _l + 8192); } while (0)
#define STAGE_B(U, TK) do { int _tk=(TK); \
    char* _l = lds + ((_tk & 1) << 16) + 32768 + ((U) << 14) + (w << 10); \
    const u16* _g = Bg + _tk * 64; \
    gload_lds16(_g + boff[U][0], _l); \
    gload_lds16(_g + boff[U][1], _l + 8192); } while (0)

template <int RELU>
__global__ __launch_bounds__(512, 2)
void gemm256(const u16* __restrict__ A, const u16* __restrict__ Bt,
             const float* __restrict__ bias, u16* __restrict__ C,
             int K, int N, int nbn) {
  __shared__ char lds[131072];
  const int tid = threadIdx.x;
  const int w = tid >> 6, lane = tid & 63;
  const int wm = w >> 2, wn = w & 3;
  const int l15 = lane & 15, l4 = lane >> 4;

  // XCD-aware swizzle (nwg % 8 == 0)
  const int nwg = (int)gridDim.x;
  const int q = nwg >> 3;
  const int wgid = ((int)blockIdx.x & 7) * q + ((int)blockIdx.x >> 3);
  const int bm = wgid / nbn, bn = wgid % nbn;

  // staging constants
  const int rb = tid >> 3;
  const int gslot = (tid & 7) ^ (rb & 7);
  unsigned aoff[2][2], boff[2][2];
#pragma unroll
  for (int u = 0; u < 2; u++)
#pragma unroll
    for (int b = 0; b < 2; b++) {
      aoff[u][b] = (unsigned)(b * 128 + u * 64 + rb) * (unsigned)K + gslot * 8;
      int brow = (2 * b + (rb >> 5)) * 64 + u * 32 + (rb & 31);
      boff[u][b] = (unsigned)brow * (unsigned)K + gslot * 8;
    }
  const u16* Ag = A + (size_t)bm * 256 * K;
  const u16* Bg = Bt + (size_t)bn * 256 * K;

  // ds_read constants (swizzled)
  const int s0 = ((l4) ^ (l15 & 7)) << 4;
  const int s1 = ((4 + l4) ^ (l15 & 7)) << 4;
  const int pA0 = (wm << 13) + (l15 << 7);
  const int pB0 = 32768 + ((wn >> 1) << 13) + ((((wn & 1) << 5) + l15) << 7);

  bf16x8 a0[4][2], a1[4][2], blo[2][2], bhi[2][2];
  f32x4 acc[8][4];
#pragma unroll
  for (int m = 0; m < 8; m++)
#pragma unroll
    for (int n = 0; n < 4; n++) acc[m][n] = f32x4{0.f, 0.f, 0.f, 0.f};

  // ---- prologue: tile0 full + tile1 {A_u0,B_u0,B_u1}
  STAGE_A(0, 0); STAGE_A(1, 0); STAGE_B(0, 0); STAGE_B(1, 0);
  STAGE_A(0, 1); STAGE_B(0, 1); STAGE_B(1, 1);
  asm volatile("s_waitcnt vmcnt(6)" ::: "memory");
  __builtin_amdgcn_s_barrier();
  // pre-read a0(0) ("P3(-1)")
#pragma unroll
  for (int mi = 0; mi < 4; mi++) {
    a0[mi][0] = *(const bf16x8*)(lds + pA0 + mi * 2048 + s0);
    a0[mi][1] = *(const bf16x8*)(lds + pA0 + mi * 2048 + s1);
  }

  const int nt = K >> 6;
  for (int t = 0; t < nt; t++) {
    const char* bp = lds + ((t & 1) << 16);
    const char* bpn = lds + (((t + 1) & 1) << 16);
    // ---------- P1: MFMA (M0,Blo); read Blo(t)+Bhi(t); stage A_u1(t+1) ----
#pragma unroll
    for (int n = 0; n < 2; n++) {                     // Blo first (same-phase use)
      blo[n][0] = *(const bf16x8*)(bp + pB0 + n * 2048 + s0);
      blo[n][1] = *(const bf16x8*)(bp + pB0 + n * 2048 + s1);
    }
#pragma unroll
    for (int n = 0; n < 2; n++) {                     // Bhi (used P2/P3)
      bhi[n][0] = *(const bf16x8*)(bp + pB0 + 16384 + n * 2048 + s0);
      bhi[n][1] = *(const bf16x8*)(bp + pB0 + 16384 + n * 2048 + s1);
    }
    if (t + 1 < nt) STAGE_A(1, t + 1);
    __builtin_amdgcn_s_barrier();
    __builtin_amdgcn_s_setprio(1);
#pragma unroll
    for (int mi = 0; mi < 4; mi++) {
      acc[mi][0] = MFMA(a0[mi][0], blo[0][0], acc[mi][0], 0, 0, 0);
      acc[mi][0] = MFMA(a0[mi][1], blo[0][1], acc[mi][0], 0, 0, 0);
      acc[mi][1] = MFMA(a0[mi][0], blo[1][0], acc[mi][1], 0, 0, 0);
      acc[mi][1] = MFMA(a0[mi][1], blo[1][1], acc[mi][1], 0, 0, 0);
    }
    __builtin_amdgcn_s_setprio(0);
    __builtin_amdgcn_s_barrier();
    // ---------- P2: MFMA (M0,Bhi); read A1(t); stage A_u0(t+2); vmcnt ----
#pragma unroll
    for (int mi = 0; mi < 4; mi++) {
      a1[mi][0] = *(const bf16x8*)(bp + 16384 + pA0 + mi * 2048 + s0);
      a1[mi][1] = *(const bf16x8*)(bp + 16384 + pA0 + mi * 2048 + s1);
    }
    if (t + 2 < nt) STAGE_A(0, t + 2);
    __builtin_amdgcn_s_barrier();
    __builtin_amdgcn_s_setprio(1);
#pragma unroll
    for (int mi = 0; mi < 4; mi++) {
      acc[mi][2] = MFMA(a0[mi][0], bhi[0][0], acc[mi][2], 0, 0, 0);
      acc[mi][2] = MFMA(a0[mi][1], bhi[0][1], acc[mi][2], 0, 0, 0);
      acc[mi][3] = MFMA(a0[mi][0], bhi[1][0], acc[mi][3], 0, 0, 0);
      acc[mi][3] = MFMA(a0[mi][1], bhi[1][1], acc[mi][3], 0, 0, 0);
    }
    __builtin_amdgcn_s_setprio(0);
    if (t + 2 < nt) { asm volatile("s_waitcnt vmcnt(6)" ::: "memory"); }
    else            { asm volatile("s_waitcnt vmcnt(0)" ::: "memory"); }
    __builtin_amdgcn_s_barrier();
    // ---------- P3: MFMA (M1,Bhi); read A0(t+1); stage B_u0(t+2) ----------
    if (t + 1 < nt) {
#pragma unroll
      for (int mi = 0; mi < 4; mi++) {
        a0[mi][0] = *(const bf16x8*)(bpn + pA0 + mi * 2048 + s0);
        a0[mi][1] = *(const bf16x8*)(bpn + pA0 + mi * 2048 + s1);
      }
    }
    if (t + 2 < nt) STAGE_B(0, t + 2);
    __builtin_amdgcn_s_barrier();
    __builtin_amdgcn_s_setprio(1);
#pragma unroll
    for (int mi = 0; mi < 4; mi++) {
      acc[4 + mi][2] = MFMA(a1[mi][0], bhi[0][0], acc[4 + mi][2], 0, 0, 0);
      acc[4 + mi][2] = MFMA(a1[mi][1], bhi[0][1], acc[4 + mi][2], 0, 0, 0);
      acc[4 + mi][3] = MFMA(a1[mi][0], bhi[1][0], acc[4 + mi][3], 0, 0, 0);
      acc[4 + mi][3] = MFMA(a1[mi][1], bhi[1][1], acc[4 + mi][3], 0, 0, 0);
    }
    __builtin_amdgcn_s_setprio(0);
    __builtin_amdgcn_s_barrier();
    // ---------- P4: MFMA (M1,Blo); stage B_u1(t+2); vmcnt ----------
    if (t + 2 < nt) STAGE_B(1, t + 2);
    __builtin_amdgcn_s_setprio(1);
#pragma unroll
    for (int mi = 0; mi < 4; mi++) {
      acc[4 + mi][0] = MFMA(a1[mi][0], blo[0][0], acc[4 + mi][0], 0, 0, 0);
      acc[4 + mi][0] = MFMA(a1[mi][1], blo[0][1], acc[4 + mi][0], 0, 0, 0);
      acc[4 + mi][1] = MFMA(a1[mi][0], blo[1][0], acc[4 + mi][1], 0, 0, 0);
      acc[4 + mi][1] = MFMA(a1[mi][1], blo[1][1], acc[4 + mi][1], 0, 0, 0);
    }
    __builtin_amdgcn_s_setprio(0);
    if (t + 2 < nt) { asm volatile("s_waitcnt vmcnt(6)" ::: "memory"); }
    else            { asm volatile("s_waitcnt vmcnt(0)" ::: "memory"); }
    __builtin_amdgcn_s_barrier();
  }

  // ---------- epilogue: bias + act + bf16 store ----------
  const int crow0 = bm * 256 + wm * 128 + l4 * 4;
  const int ccol0 = bn * 256 + wn * 64 + l15;
#pragma unroll
  for (int n = 0; n < 4; n++) {
    const int col = ccol0 + n * 16;
    const float bv = bias[col];
#pragma unroll
    for (int m = 0; m < 8; m++) {
#pragma unroll
      for (int r = 0; r < 4; r++) {
        const int row = crow0 + m * 16 + r;
        float v = acc[m][n][r] + bv;
        if (RELU) v = fmaxf(v, 0.0f);
        C[(size_t)row * N + col] = f2bf(v);
      }
    }
  }
}

// ---------------- 128x128 GEMM (validated) for the small head ----
template <int RELU, int F32OUT, int NCHECK>
__global__ __launch_bounds__(256, 2)
void gemm_bt(const u16* __restrict__ A, const u16* __restrict__ Bt,
             const float* __restrict__ bias, void* __restrict__ C,
             int K, int N, int ldc) {
  __shared__ u16 As[128 * 32];
  __shared__ u16 Bs[128 * 32];
  const int t = threadIdx.x;
  const int w = t >> 6, lane = t & 63;
  const int bm = blockIdx.x, bn = blockIdx.y;
  const int wr = (w >> 1) * 64, wc = (w & 1) * 64;

  f32x4 acc[4][4];
#pragma unroll
  for (int m = 0; m < 4; m++)
#pragma unroll
    for (int n = 0; n < 4; n++) acc[m][n] = f32x4{0.f, 0.f, 0.f, 0.f};

  const u16* gA = A + (size_t)(bm * 128 + (t >> 2)) * K + (t & 3) * 8;
  const u16* gB = Bt + (size_t)(bn * 128 + (t >> 2)) * K + (t & 3) * 8;
  u16* lA = As + w * 512;
  u16* lB = Bs + w * 512;
  const size_t row64 = (size_t)64 * K;

  for (int k0 = 0; k0 < K; k0 += 32) {
    gload_lds16(gA + k0, lA);
    gload_lds16(gA + row64 + k0, lA + 2048);
    gload_lds16(gB + k0, lB);
    gload_lds16(gB + row64 + k0, lB + 2048);
    asm volatile("s_waitcnt vmcnt(0)" ::: "memory");
    __syncthreads();

    const u16* pa = As + (wr + (lane & 15)) * 32 + (lane >> 4) * 8;
    const u16* pb = Bs + (wc + (lane & 15)) * 32 + (lane >> 4) * 8;
    bf16x8 af[4], bfr[4];
#pragma unroll
    for (int m = 0; m < 4; m++) af[m] = *(const bf16x8*)(pa + m * 512);
#pragma unroll
    for (int n = 0; n < 4; n++) bfr[n] = *(const bf16x8*)(pb + n * 512);
#pragma unroll
    for (int m = 0; m < 4; m++)
#pragma unroll
      for (int n = 0; n < 4; n++)
        acc[m][n] = MFMA(af[m], bfr[n], acc[m][n], 0, 0, 0);
    __syncthreads();
  }

  const int crow = bm * 128 + wr + (lane >> 4) * 4;
  const int ccol = bn * 128 + wc + (lane & 15);
#pragma unroll
  for (int n = 0; n < 4; n++) {
    const int col = ccol + n * 16;
    if (NCHECK && col >= N) continue;
    const float bv = bias[col];
#pragma unroll
    for (int m = 0; m < 4; m++) {
#pragma unroll
      for (int r = 0; r < 4; r++) {
        const int row = crow + m * 16 + r;
        float v = acc[m][n][r] + bv;
        if (RELU) v = fmaxf(v, 0.0f);
        if (F32OUT)
          ((float*)C)[(size_t)row * ldc + col] = v;
        else
          ((u16*)C)[(size_t)row * ldc + col] = f2bf(v);
      }
    }
  }
}

// ---------------- row softmax: one wave per row ----------------
__global__ __launch_bounds__(256) void softmax_rows(const float* __restrict__ logits,
                                                    float* __restrict__ out,
                                                    int rows, int cols) {
  const int wid = (blockIdx.x * 256 + threadIdx.x) >> 6;
  const int lane = threadIdx.x & 63;
  if (wid >= rows) return;
  const float* rp = logits + (size_t)wid * cols;
  float v[16];
  float mx = -1e30f;
#pragma unroll
  for (int j = 0; j < 16; j++) {
    int c = lane + j * 64;
    v[j] = (c < cols) ? rp[c] : -1e30f;
    mx = fmaxf(mx, v[j]);
  }
#pragma unroll
  for (int s = 32; s; s >>= 1) mx = fmaxf(mx, __shfl_xor(mx, s));
  float sum = 0.f;
#pragma unroll
  for (int j = 0; j < 16; j++) {
    v[j] = __expf(v[j] - mx);
    sum += v[j];
  }
#pragma unroll
  for (int s = 32; s; s >>= 1) sum += __shfl_xor(sum, s);
  const float inv = 1.0f / sum;
  float* op = out + (size_t)wid * cols;
#pragma unroll
  for (int j = 0; j < 16; j++) {
    int c = lane + j * 64;
    if (c < cols) op[c] = v[j] * inv;
  }
}

extern "C" void kernel_launch(void* const* d_in, const int* in_sizes, int n_in,
                              void* d_out, int out_size, void* d_ws, size_t ws_size,
                              hipStream_t stream) {
  const float* x  = (const float*)d_in[0];
  const float* W1 = (const float*)d_in[1];
  const float* b1 = (const float*)d_in[2];
  const float* W2 = (const float*)d_in[3];
  const float* b2 = (const float*)d_in[4];
  const float* Wc = (const float*)d_in[5];
  const float* bc = (const float*)d_in[6];
  float* out = (float*)d_out;

  const int B = 8192, D = 4096, DOUT = 1000, DOUTP = 1024;

  char* ws = (char*)d_ws;
  u16* xb     = (u16*)(ws + 0);                       // 8192x4096 bf16
  u16* h      = (u16*)(ws + 67108864);                // 8192x4096 bf16
  u16* feats  = xb;                                   // alias: x dead after GEMM1
  u16* W1t    = (u16*)(ws + 134217728);               // 4096x4096 bf16 [N][K]
  u16* W2t    = (u16*)(ws + 167772160);               // 4096x4096 bf16 [N][K]
  u16* Wct    = (u16*)(ws + 201326592);               // 1024x4096 bf16 [Npad][K]
  float* logits = (float*)(ws + 209715200);           // 8192x1000 f32

  // stage 0: dtype conversions / transposes
  cvt_f32_bf16<<<(B * D / 4 + 255) / 256, 256, 0, stream>>>(x, xb, B * D / 4);
  transpose_w<<<dim3(D / 32, D / 32), 256, 0, stream>>>(W1, W1t, D, D);
  transpose_w<<<dim3(D / 32, D / 32), 256, 0, stream>>>(W2, W2t, D, D);
  transpose_w<<<dim3(DOUTP / 32, D / 32), 256, 0, stream>>>(Wc, Wct, D, DOUT);

  // stage 1/2: 256^2 pipelined 8-phase GEMMs (grid 32x16 = 512 blocks)
  gemm256<1><<<dim3(512), 512, 0, stream>>>(xb, W1t, b1, h, D, D, D / 256);
  gemm256<1><<<dim3(512), 512, 0, stream>>>(h, W2t, b2, feats, D, D, D / 256);
  // stage 3: logits = feats@Wc+bc (f32 out, N bounds-checked)
  gemm_bt<0, 1, 1><<<dim3(B / 128, DOUTP / 128), 256, 0, stream>>>(feats, Wct, bc, logits, D, DOUT, DOUT);
  // stage 4: softmax rows
  softmax_rows<<<(B * 64 + 255) / 256, 256, 0, stream>>>(logits, out, B, DOUT);
}

// Round 4
// 868.315 us; speedup vs baseline: 1.1585x; 1.0057x over previous
//
#include <hip/hip_runtime.h>
#include <hip/hip_bf16.h>

typedef unsigned short u16;
typedef __attribute__((ext_vector_type(8))) short bf16x8;
typedef __attribute__((ext_vector_type(4))) float f32x4;

#define MFMA __builtin_amdgcn_mfma_f32_16x16x32_bf16

__device__ __forceinline__ u16 f2bf(float f) {
  union { float f; unsigned u; } v; v.f = f;
  unsigned r = v.u + 0x7fffu + ((v.u >> 16) & 1u);
  return (u16)(r >> 16);
}

__device__ __forceinline__ void gload_lds16(const void* g, void* l) {
  __builtin_amdgcn_global_load_lds(
      (const __attribute__((address_space(1))) unsigned int*)g,
      (__attribute__((address_space(3))) unsigned int*)l, 16, 0, 0);
}

// LDS byte-offset of a generic pointer into __shared__ (as3 is 32-bit)
#define LDS_OFF(p) ((unsigned)(size_t)(__attribute__((address_space(3))) char*)(p))

// inline-asm ds_read_b128: invisible to compiler alias analysis, so no
// compiler-inserted vmcnt drains vs global_load_lds (round-4 theory).
#define DSR(dst, addr, off) \
  asm volatile("ds_read_b128 %0, %1 offset:" off : "=v"(dst) : "v"(addr))

// ---------------- convert f32 -> bf16, vectorized ----------------
__global__ __launch_bounds__(256) void cvt_f32_bf16(const float* __restrict__ in,
                                                    u16* __restrict__ out, int n4) {
  int i = blockIdx.x * 256 + threadIdx.x;
  if (i < n4) {
    float4 v = ((const float4*)in)[i];
    ushort4 o;
    o.x = f2bf(v.x); o.y = f2bf(v.y); o.z = f2bf(v.z); o.w = f2bf(v.w);
    ((ushort4*)out)[i] = o;
  }
}

// -------- transpose [K][N] f32 -> [Npad][K] bf16 (pad rows = 0) --------
__global__ __launch_bounds__(256) void transpose_w(const float* __restrict__ W,
                                                   u16* __restrict__ Wt,
                                                   int K, int N) {
  __shared__ float tile[32][33];
  const int tx = threadIdx.x & 31, ty = threadIdx.x >> 5;  // 32 x 8
  const int n0 = blockIdx.x * 32, k0 = blockIdx.y * 32;
#pragma unroll
  for (int i = 0; i < 32; i += 8) {
    int k = k0 + ty + i, n = n0 + tx;
    tile[ty + i][tx] = (n < N) ? W[(size_t)k * N + n] : 0.0f;
  }
  __syncthreads();
#pragma unroll
  for (int i = 0; i < 32; i += 8) {
    int n = n0 + ty + i, k = k0 + tx;
    Wt[(size_t)n * K + k] = f2bf(tile[tx][ty + i]);
  }
}

// =====================================================================
// 256x256 8-phase GEMM, asm ds_read (round-4).
// BK=64, 8 waves 2Mx4N, per-wave 128x64. LDS 128KB dbuf, XOR-swizzled.
// Phases: P1=(M0,Blo) reads a0+blo; P2=(M0,Bhi) reads bhi; P3=(M1,Bhi)
// reads a1; P4=(M1,Blo) no reads. Stages: P1:A_u1(t+1) P2:A_u0(t+2)
// P3:B_u0(t+2) P4:B_u1(t+2). vmcnt(6) once per tile at end-P4.
// =====================================================================
#define STAGE_A(U, TK) do { int _tk=(TK); \
    char* _l = lds + ((_tk & 1) << 16) + ((U) << 14) + (w << 10); \
    const u16* _g = Ag + _tk * 64; \
    gload_lds16(_g + aoff[U][0], _l); \
    gload_lds16(_g + aoff[U][1], _l + 8192); } while (0)
#define STAGE_B(U, TK) do { int _tk=(TK); \
    char* _l = lds + ((_tk & 1) << 16) + 32768 + ((U) << 14) + (w << 10); \
    const u16* _g = Bg + _tk * 64; \
    gload_lds16(_g + boff[U][0], _l); \
    gload_lds16(_g + boff[U][1], _l + 8192); } while (0)

template <int RELU>
__global__ __launch_bounds__(512, 2)
void gemm256(const u16* __restrict__ A, const u16* __restrict__ Bt,
             const float* __restrict__ bias, u16* __restrict__ C,
             int K, int N, int nbn) {
  __shared__ char lds[131072];
  const int tid = threadIdx.x;
  const int w = tid >> 6, lane = tid & 63;
  const int wm = w >> 2, wn = w & 3;
  const int l15 = lane & 15, l4 = lane >> 4;

  // XCD-aware swizzle (nwg % 8 == 0)
  const int nwg = (int)gridDim.x;
  const int q = nwg >> 3;
  const int wgid = ((int)blockIdx.x & 7) * q + ((int)blockIdx.x >> 3);
  const int bm = wgid / nbn, bn = wgid % nbn;

  // staging constants
  const int rb = tid >> 3;
  const int gslot = (tid & 7) ^ (rb & 7);
  unsigned aoff[2][2], boff[2][2];
#pragma unroll
  for (int u = 0; u < 2; u++)
#pragma unroll
    for (int b = 0; b < 2; b++) {
      aoff[u][b] = (unsigned)(b * 128 + u * 64 + rb) * (unsigned)K + gslot * 8;
      int brow = (2 * b + (rb >> 5)) * 64 + u * 32 + (rb & 31);
      boff[u][b] = (unsigned)brow * (unsigned)K + gslot * 8;
    }
  const u16* Ag = A + (size_t)bm * 256 * K;
  const u16* Bg = Bt + (size_t)bn * 256 * K;

  // ds_read base offsets (swizzled): slot(ks) = (ks*4 + l4) ^ (l15 & 7)
  const unsigned ldsbase = LDS_OFF(lds);
  const int s0 = ((l4) ^ (l15 & 7)) << 4;
  const int s1 = ((4 + l4) ^ (l15 & 7)) << 4;
  const int pA0 = (wm << 13) + (l15 << 7);
  const int pB0 = 32768 + ((wn >> 1) << 13) + ((((wn & 1) << 5) + l15) << 7);

  bf16x8 a0[4][2], a1[4][2], blo[2][2], bhi[2][2];
  f32x4 acc[8][4];
#pragma unroll
  for (int m = 0; m < 8; m++)
#pragma unroll
    for (int n = 0; n < 4; n++) acc[m][n] = f32x4{0.f, 0.f, 0.f, 0.f};

  // ---- prologue: tile0 full + tile1 {A_u0,B_u0,B_u1}; 3 stages in flight
  STAGE_A(0, 0); STAGE_A(1, 0); STAGE_B(0, 0); STAGE_B(1, 0);
  STAGE_A(0, 1); STAGE_B(0, 1); STAGE_B(1, 1);
  asm volatile("s_waitcnt vmcnt(6)" ::: "memory");
  __builtin_amdgcn_s_barrier();

  const int nt = K >> 6;
  for (int t = 0; t < nt; t++) {
    const unsigned bufo = ldsbase + ((t & 1) << 16);
    const unsigned aAs0 = bufo + pA0 + s0;
    const unsigned aAs1 = bufo + pA0 + s1;
    const unsigned aBs0 = bufo + pB0 + s0;
    const unsigned aBs1 = bufo + pB0 + s1;
    // ---------- P1: read a0(8)+blo(4); stage A_u1(t+1); MFMA (M0,Blo) ----
    DSR(a0[0][0], aAs0, "0");    DSR(a0[1][0], aAs0, "2048");
    DSR(a0[2][0], aAs0, "4096"); DSR(a0[3][0], aAs0, "6144");
    DSR(a0[0][1], aAs1, "0");    DSR(a0[1][1], aAs1, "2048");
    DSR(a0[2][1], aAs1, "4096"); DSR(a0[3][1], aAs1, "6144");
    DSR(blo[0][0], aBs0, "0");   DSR(blo[1][0], aBs0, "2048");
    DSR(blo[0][1], aBs1, "0");   DSR(blo[1][1], aBs1, "2048");
    if (t + 1 < nt) STAGE_A(1, t + 1);
    __builtin_amdgcn_s_barrier();
    asm volatile("s_waitcnt lgkmcnt(0)" ::: "memory");
    __builtin_amdgcn_sched_barrier(0);
    __builtin_amdgcn_s_setprio(1);
#pragma unroll
    for (int mi = 0; mi < 4; mi++) {
      acc[mi][0] = MFMA(a0[mi][0], blo[0][0], acc[mi][0], 0, 0, 0);
      acc[mi][1] = MFMA(a0[mi][0], blo[1][0], acc[mi][1], 0, 0, 0);
    }
#pragma unroll
    for (int mi = 0; mi < 4; mi++) {
      acc[mi][0] = MFMA(a0[mi][1], blo[0][1], acc[mi][0], 0, 0, 0);
      acc[mi][1] = MFMA(a0[mi][1], blo[1][1], acc[mi][1], 0, 0, 0);
    }
    __builtin_amdgcn_s_setprio(0);
    __builtin_amdgcn_s_barrier();
    // ---------- P2: read bhi(4); stage A_u0(t+2); MFMA (M0,Bhi) ----------
    DSR(bhi[0][0], aBs0, "16384"); DSR(bhi[1][0], aBs0, "18432");
    DSR(bhi[0][1], aBs1, "16384"); DSR(bhi[1][1], aBs1, "18432");
    if (t + 2 < nt) STAGE_A(0, t + 2);
    __builtin_amdgcn_s_barrier();
    asm volatile("s_waitcnt lgkmcnt(0)" ::: "memory");
    __builtin_amdgcn_sched_barrier(0);
    __builtin_amdgcn_s_setprio(1);
#pragma unroll
    for (int mi = 0; mi < 4; mi++) {
      acc[mi][2] = MFMA(a0[mi][0], bhi[0][0], acc[mi][2], 0, 0, 0);
      acc[mi][3] = MFMA(a0[mi][0], bhi[1][0], acc[mi][3], 0, 0, 0);
    }
#pragma unroll
    for (int mi = 0; mi < 4; mi++) {
      acc[mi][2] = MFMA(a0[mi][1], bhi[0][1], acc[mi][2], 0, 0, 0);
      acc[mi][3] = MFMA(a0[mi][1], bhi[1][1], acc[mi][3], 0, 0, 0);
    }
    __builtin_amdgcn_s_setprio(0);
    __builtin_amdgcn_s_barrier();
    // ---------- P3: read a1(8); stage B_u0(t+2); MFMA (M1,Bhi) ----------
    DSR(a1[0][0], aAs0, "16384"); DSR(a1[1][0], aAs0, "18432");
    DSR(a1[2][0], aAs0, "20480"); DSR(a1[3][0], aAs0, "22528");
    DSR(a1[0][1], aAs1, "16384"); DSR(a1[1][1], aAs1, "18432");
    DSR(a1[2][1], aAs1, "20480"); DSR(a1[3][1], aAs1, "22528");
    if (t + 2 < nt) STAGE_B(0, t + 2);
    __builtin_amdgcn_s_barrier();
    asm volatile("s_waitcnt lgkmcnt(0)" ::: "memory");
    __builtin_amdgcn_sched_barrier(0);
    __builtin_amdgcn_s_setprio(1);
#pragma unroll
    for (int mi = 0; mi < 4; mi++) {
      acc[4 + mi][2] = MFMA(a1[mi][0], bhi[0][0], acc[4 + mi][2], 0, 0, 0);
      acc[4 + mi][3] = MFMA(a1[mi][0], bhi[1][0], acc[4 + mi][3], 0, 0, 0);
    }
#pragma unroll
    for (int mi = 0; mi < 4; mi++) {
      acc[4 + mi][2] = MFMA(a1[mi][1], bhi[0][1], acc[4 + mi][2], 0, 0, 0);
      acc[4 + mi][3] = MFMA(a1[mi][1], bhi[1][1], acc[4 + mi][3], 0, 0, 0);
    }
    __builtin_amdgcn_s_setprio(0);
    __builtin_amdgcn_s_barrier();
    // ---------- P4: stage B_u1(t+2); MFMA (M1,Blo); vmcnt; barrier ------
    if (t + 2 < nt) STAGE_B(1, t + 2);
    __builtin_amdgcn_s_setprio(1);
#pragma unroll
    for (int mi = 0; mi < 4; mi++) {
      acc[4 + mi][0] = MFMA(a1[mi][0], blo[0][0], acc[4 + mi][0], 0, 0, 0);
      acc[4 + mi][1] = MFMA(a1[mi][0], blo[1][0], acc[4 + mi][1], 0, 0, 0);
    }
#pragma unroll
    for (int mi = 0; mi < 4; mi++) {
      acc[4 + mi][0] = MFMA(a1[mi][1], blo[0][1], acc[4 + mi][0], 0, 0, 0);
      acc[4 + mi][1] = MFMA(a1[mi][1], blo[1][1], acc[4 + mi][1], 0, 0, 0);
    }
    __builtin_amdgcn_s_setprio(0);
    if (t + 2 < nt) { asm volatile("s_waitcnt vmcnt(6)" ::: "memory"); }
    else            { asm volatile("s_waitcnt vmcnt(0)" ::: "memory"); }
    __builtin_amdgcn_s_barrier();
  }

  // ---------- epilogue: bias + act + bf16 store ----------
  const int crow0 = bm * 256 + wm * 128 + l4 * 4;
  const int ccol0 = bn * 256 + wn * 64 + l15;
#pragma unroll
  for (int n = 0; n < 4; n++) {
    const int col = ccol0 + n * 16;
    const float bv = bias[col];
#pragma unroll
    for (int m = 0; m < 8; m++) {
#pragma unroll
      for (int r = 0; r < 4; r++) {
        const int row = crow0 + m * 16 + r;
        float v = acc[m][n][r] + bv;
        if (RELU) v = fmaxf(v, 0.0f);
        C[(size_t)row * N + col] = f2bf(v);
      }
    }
  }
}

// ---------------- 128x128 GEMM (validated) for the small head ----
template <int RELU, int F32OUT, int NCHECK>
__global__ __launch_bounds__(256, 2)
void gemm_bt(const u16* __restrict__ A, const u16* __restrict__ Bt,
             const float* __restrict__ bias, void* __restrict__ C,
             int K, int N, int ldc) {
  __shared__ u16 As[128 * 32];
  __shared__ u16 Bs[128 * 32];
  const int t = threadIdx.x;
  const int w = t >> 6, lane = t & 63;
  const int bm = blockIdx.x, bn = blockIdx.y;
  const int wr = (w >> 1) * 64, wc = (w & 1) * 64;

  f32x4 acc[4][4];
#pragma unroll
  for (int m = 0; m < 4; m++)
#pragma unroll
    for (int n = 0; n < 4; n++) acc[m][n] = f32x4{0.f, 0.f, 0.f, 0.f};

  const u16* gA = A + (size_t)(bm * 128 + (t >> 2)) * K + (t & 3) * 8;
  const u16* gB = Bt + (size_t)(bn * 128 + (t >> 2)) * K + (t & 3) * 8;
  u16* lA = As + w * 512;
  u16* lB = Bs + w * 512;
  const size_t row64 = (size_t)64 * K;

  for (int k0 = 0; k0 < K; k0 += 32) {
    gload_lds16(gA + k0, lA);
    gload_lds16(gA + row64 + k0, lA + 2048);
    gload_lds16(gB + k0, lB);
    gload_lds16(gB + row64 + k0, lB + 2048);
    asm volatile("s_waitcnt vmcnt(0)" ::: "memory");
    __syncthreads();

    const u16* pa = As + (wr + (lane & 15)) * 32 + (lane >> 4) * 8;
    const u16* pb = Bs + (wc + (lane & 15)) * 32 + (lane >> 4) * 8;
    bf16x8 af[4], bfr[4];
#pragma unroll
    for (int m = 0; m < 4; m++) af[m] = *(const bf16x8*)(pa + m * 512);
#pragma unroll
    for (int n = 0; n < 4; n++) bfr[n] = *(const bf16x8*)(pb + n * 512);
#pragma unroll
    for (int m = 0; m < 4; m++)
#pragma unroll
      for (int n = 0; n < 4; n++)
        acc[m][n] = MFMA(af[m], bfr[n], acc[m][n], 0, 0, 0);
    __syncthreads();
  }

  const int crow = bm * 128 + wr + (lane >> 4) * 4;
  const int ccol = bn * 128 + wc + (lane & 15);
#pragma unroll
  for (int n = 0; n < 4; n++) {
    const int col = ccol + n * 16;
    if (NCHECK && col >= N) continue;
    const float bv = bias[col];
#pragma unroll
    for (int m = 0; m < 4; m++) {
#pragma unroll
      for (int r = 0; r < 4; r++) {
        const int row = crow + m * 16 + r;
        float v = acc[m][n][r] + bv;
        if (RELU) v = fmaxf(v, 0.0f);
        if (F32OUT)
          ((float*)C)[(size_t)row * ldc + col] = v;
        else
          ((u16*)C)[(size_t)row * ldc + col] = f2bf(v);
      }
    }
  }
}

// ---------------- row softmax: one wave per row ----------------
__global__ __launch_bounds__(256) void softmax_rows(const float* __restrict__ logits,
                                                    float* __restrict__ out,
                                                    int rows, int cols) {
  const int wid = (blockIdx.x * 256 + threadIdx.x) >> 6;
  const int lane = threadIdx.x & 63;
  if (wid >= rows) return;
  const float* rp = logits + (size_t)wid * cols;
  float v[16];
  float mx = -1e30f;
#pragma unroll
  for (int j = 0; j < 16; j++) {
    int c = lane + j * 64;
    v[j] = (c < cols) ? rp[c] : -1e30f;
    mx = fmaxf(mx, v[j]);
  }
#pragma unroll
  for (int s = 32; s; s >>= 1) mx = fmaxf(mx, __shfl_xor(mx, s));
  float sum = 0.f;
#pragma unroll
  for (int j = 0; j < 16; j++) {
    v[j] = __expf(v[j] - mx);
    sum += v[j];
  }
#pragma unroll
  for (int s = 32; s; s >>= 1) sum += __shfl_xor(sum, s);
  const float inv = 1.0f / sum;
  float* op = out + (size_t)wid * cols;
#pragma unroll
  for (int j = 0; j < 16; j++) {
    int c = lane + j * 64;
    if (c < cols) op[c] = v[j] * inv;
  }
}

extern "C" void kernel_launch(void* const* d_in, const int* in_sizes, int n_in,
                              void* d_out, int out_size, void* d_ws, size_t ws_size,
                              hipStream_t stream) {
  const float* x  = (const float*)d_in[0];
  const float* W1 = (const float*)d_in[1];
  const float* b1 = (const float*)d_in[2];
  const float* W2 = (const float*)d_in[3];
  const float* b2 = (const float*)d_in[4];
  const float* Wc = (const float*)d_in[5];
  const float* bc = (const float*)d_in[6];
  float* out = (float*)d_out;

  const int B = 8192, D = 4096, DOUT = 1000, DOUTP = 1024;

  char* ws = (char*)d_ws;
  u16* xb     = (u16*)(ws + 0);                       // 8192x4096 bf16
  u16* h      = (u16*)(ws + 67108864);                // 8192x4096 bf16
  u16* feats  = xb;                                   // alias: x dead after GEMM1
  u16* W1t    = (u16*)(ws + 134217728);               // 4096x4096 bf16 [N][K]
  u16* W2t    = (u16*)(ws + 167772160);               // 4096x4096 bf16 [N][K]
  u16* Wct    = (u16*)(ws + 201326592);               // 1024x4096 bf16 [Npad][K]
  float* logits = (float*)(ws + 209715200);           // 8192x1000 f32

  // stage 0: dtype conversions / transposes
  cvt_f32_bf16<<<(B * D / 4 + 255) / 256, 256, 0, stream>>>(x, xb, B * D / 4);
  transpose_w<<<dim3(D / 32, D / 32), 256, 0, stream>>>(W1, W1t, D, D);
  transpose_w<<<dim3(D / 32, D / 32), 256, 0, stream>>>(W2, W2t, D, D);
  transpose_w<<<dim3(DOUTP / 32, D / 32), 256, 0, stream>>>(Wc, Wct, D, DOUT);

  // stage 1/2: 256^2 8-phase GEMMs, asm ds_read (grid 32x16 = 512 blocks)
  gemm256<1><<<dim3(512), 512, 0, stream>>>(xb, W1t, b1, h, D, D, D / 256);
  gemm256<1><<<dim3(512), 512, 0, stream>>>(h, W2t, b2, feats, D, D, D / 256);
  // stage 3: logits = feats@Wc+bc (f32 out, N bounds-checked)
  gemm_bt<0, 1, 1><<<dim3(B / 128, DOUTP / 128), 256, 0, stream>>>(feats, Wct, bc, logits, D, DOUT, DOUT);
  // stage 4: softmax rows
  softmax_rows<<<(B * 64 + 255) / 256, 256, 0, stream>>>(logits, out, B, DOUT);
}